// Round 14
// baseline (465.145 us; speedup 1.0000x reference)
//
#include <hip/hip_runtime.h>
#include <math.h>

// fp32 ws layout (floats), proven (R2/R7/R13):
#define OFF0 0
#define OFF1 18432
#define OFF2 83968
#define OFF3 149504
#define OFF4 215040
#define OFFB 216064

__global__ void prep_params(
    const float* __restrict__ w0, const float* __restrict__ w1,
    const float* __restrict__ w2, const float* __restrict__ w3,
    const float* __restrict__ w4,
    const float* __restrict__ m0, const float* __restrict__ m1,
    const float* __restrict__ m2, const float* __restrict__ m3,
    const float* __restrict__ m4,
    float* __restrict__ ws)
{
    int idx = blockIdx.x * blockDim.x + threadIdx.x;
    if (idx >= 2056) return;
    int layer, b, o;
    if (idx < 2048) { layer = idx >> 9; b = (idx >> 7) & 3; o = idx & 127; }
    else { layer = 4; int r = idx - 2048; b = r >> 1; o = r & 1; }

    const float* w; const float* m; int Fm, O, Fp; int off;
    switch (layer) {
      case 0:  w = w0; m = m0; Fm = 35;  O = 128; Fp = 36;  off = OFF0; break;
      case 1:  w = w1; m = m1; Fm = 128; O = 128; Fp = 128; off = OFF1; break;
      case 2:  w = w2; m = m2; Fm = 128; O = 128; Fp = 128; off = OFF2; break;
      case 3:  w = w3; m = m3; Fm = 128; O = 128; Fp = 128; off = OFF3; break;
      default: w = w4; m = m4; Fm = 128; O = 2;   Fp = 128; off = OFF4; break;
    }

    float ss = 0.f;
    for (int f = 0; f < Fm; ++f) {
        float v = w[f * O + o] * m[(b * Fm + f) * O + o];
        ss += v * v;
    }
    float r = 1.0f / fmaxf(sqrtf(ss), 1e-12f);

    float* pT = ws + off + (b * O + o) * Fp;
    for (int f = 0; f < Fm; ++f) {
        float v = w[f * O + o] * m[(b * Fm + f) * O + o];
        pT[f] = v * r;
    }
    if (layer == 0) pT[35] = 0.f;           // zero-pad fan-in 35 -> 36
    ws[OFFB + layer * 512 + b * 128 + o] = w[Fm * O + o];
}

// Four points (rows rb+0/8192/16384/24576, shared swizzle salt s) x 8 outputs.
// Weights via wave-uniform s_load (pb, bs); hidden via swizzled ds_read_b128.
// Row layout: 128 floats = 32 float4-groups; group' = k ^ s (bijection, R13-proven
// conflict-free: SQ_LDS_BANK_CONFLICT == 0).
template<int F>
__device__ __forceinline__ void accum4p(const float* __restrict__ rb, int s,
                                        const float* __restrict__ pb,
                                        const float* __restrict__ bs,
                                        float* a0, float* a1, float* a2, float* a3)
{
    #pragma unroll
    for (int j = 0; j < 8; ++j) { a0[j] = bs[j]; a1[j] = bs[j]; a2[j] = bs[j]; a3[j] = bs[j]; }
    #pragma unroll 2
    for (int k = 0; k < (F + 3) / 4; ++k) {
        const int off = ((k ^ s) << 2);
        float4 h0 = *(const float4*)(rb + off);
        float4 h1 = *(const float4*)(rb + 8192 + off);
        float4 h2 = *(const float4*)(rb + 16384 + off);
        float4 h3 = *(const float4*)(rb + 24576 + off);
        #pragma unroll
        for (int j = 0; j < 8; ++j) {
            const float* pr = pb + j * F + k * 4;   // uniform -> s_load_dwordx4
            a0[j] = fmaf(h0.x, pr[0], a0[j]);  a1[j] = fmaf(h1.x, pr[0], a1[j]);
            a2[j] = fmaf(h2.x, pr[0], a2[j]);  a3[j] = fmaf(h3.x, pr[0], a3[j]);
            a0[j] = fmaf(h0.y, pr[1], a0[j]);  a1[j] = fmaf(h1.y, pr[1], a1[j]);
            a2[j] = fmaf(h2.y, pr[1], a2[j]);  a3[j] = fmaf(h3.y, pr[1], a3[j]);
            a0[j] = fmaf(h0.z, pr[2], a0[j]);  a1[j] = fmaf(h1.z, pr[2], a1[j]);
            a2[j] = fmaf(h2.z, pr[2], a2[j]);  a3[j] = fmaf(h3.z, pr[2], a3[j]);
            a0[j] = fmaf(h0.w, pr[3], a0[j]);  a1[j] = fmaf(h1.w, pr[3], a1[j]);
            a2[j] = fmaf(h2.w, pr[3], a2[j]);  a3[j] = fmaf(h3.w, pr[3], a3[j]);
        }
    }
}

__device__ __forceinline__ float4 interp_pt(const float* __restrict__ lat,
                                            int b, int pg, int c0)
{
    const int y = pg >> 8, x = pg & 255;
    const float sy = (y + 0.5f) * 0.25f - 0.5f;
    const float sx = (x + 0.5f) * 0.25f - 0.5f;
    const float fy = floorf(sy), fx = floorf(sx);
    const float ty = sy - fy, tx = sx - fx;
    int y0 = (int)fy, x0 = (int)fx;
    const int y1 = min(y0 + 1, 63); y0 = max(y0, 0);
    const int x1 = min(x0 + 1, 63); x0 = max(x0, 0);
    const float* base = lat + ((size_t)b << 17) + c0;
    const float4 v00 = *(const float4*)(base + (y0 * 64 + x0) * 32);
    const float4 v01 = *(const float4*)(base + (y0 * 64 + x1) * 32);
    const float4 v10 = *(const float4*)(base + (y1 * 64 + x0) * 32);
    const float4 v11 = *(const float4*)(base + (y1 * 64 + x1) * 32);
    const float w00 = (1.f - ty) * (1.f - tx), w01 = (1.f - ty) * tx;
    const float w10 = ty * (1.f - tx),         w11 = ty * tx;
    float4 r;
    r.x = w00 * v00.x + w01 * v01.x + w10 * v10.x + w11 * v11.x;
    r.y = w00 * v00.y + w01 * v01.y + w10 * v10.y + w11 * v11.y;
    r.z = w00 * v00.z + w01 * v01.z + w10 * v10.z + w11 * v11.z;
    r.w = w00 * v00.w + w01 * v01.w + w10 * v10.w + w11 * v11.w;
    return r;
}

__global__ __launch_bounds__(512, 2)
void hyponet_main(const float* __restrict__ coord,
                  const float* __restrict__ lat,
                  const float* __restrict__ ws,
                  float* __restrict__ out)
{
    extern __shared__ float hsf[];   // 128 KB dynamic: 256 points x 32 swizzled groups
    const int tid  = threadIdx.x;
    const int lane = tid & 63;
    const int wv   = tid >> 6;               // 8 waves: o-block owner
    const int b    = blockIdx.x >> 8;        // 256 tiles per batch
    const int tile = blockIdx.x & 255;
    const int pgB  = tile * 256;             // base point of this block
    const int s    = lane & 31;              // swizzle salt (same for all 4 rows)
    float* rb = hsf + lane * 128;            // rows at +0, +8192, +16384, +24576

    // ---- bilinear upsample + coord for the lane's four points
    {
        const int c0 = wv * 4;               // each wave fills group wv
        #pragma unroll
        for (int j = 0; j < 4; ++j)
            *(float4*)(rb + j * 8192 + ((wv ^ s) << 2)) =
                interp_pt(lat, b, pgB + j * 64 + lane, c0);
        if (wv == 0) {                       // group 8: {c0,c1,c2,0}
            #pragma unroll
            for (int j = 0; j < 4; ++j) {
                const float* cp = coord + ((size_t)b * 65536 + pgB + j * 64 + lane) * 3;
                *(float4*)(rb + j * 8192 + ((8 ^ s) << 2)) =
                    make_float4(cp[0], cp[1], cp[2], 0.f);
            }
        }
    }
    __syncthreads();

    const int ob0 = __builtin_amdgcn_readfirstlane(wv * 16);
    const int ob1 = __builtin_amdgcn_readfirstlane(wv * 16 + 8);
    float a0[16], a1[16], a2[16], a3[16];

    // ---- all 5 layers share the pattern; L0 has F=36, rest F=128
    #pragma unroll 1
    for (int L = 0; L <= 3; ++L) {
        if (L == 0) {
            accum4p<36>(rb, s, ws + OFF0 + (b * 128 + ob0) * 36,
                        ws + OFFB + b * 128 + ob0, a0, a1, a2, a3);
            accum4p<36>(rb, s, ws + OFF0 + (b * 128 + ob1) * 36,
                        ws + OFFB + b * 128 + ob1, a0 + 8, a1 + 8, a2 + 8, a3 + 8);
        } else {
            const int off_w = (L == 1) ? OFF1 : (L == 2) ? OFF2 : OFF3;
            accum4p<128>(rb, s, ws + off_w + (b * 128 + ob0) * 128,
                         ws + OFFB + L * 512 + b * 128 + ob0, a0, a1, a2, a3);
            accum4p<128>(rb, s, ws + off_w + (b * 128 + ob1) * 128,
                         ws + OFFB + L * 512 + b * 128 + ob1, a0 + 8, a1 + 8, a2 + 8, a3 + 8);
        }
        #pragma unroll
        for (int j = 0; j < 16; ++j) {
            a0[j] = __sinf(a0[j]); a1[j] = __sinf(a1[j]);
            a2[j] = __sinf(a2[j]); a3[j] = __sinf(a3[j]);
        }
        __syncthreads();
        #pragma unroll
        for (int jj = 0; jj < 4; ++jj) {
            const int off = (((wv * 4 + jj) ^ s) << 2);
            *(float4*)(rb + off)         = make_float4(a0[jj*4], a0[jj*4+1], a0[jj*4+2], a0[jj*4+3]);
            *(float4*)(rb + 8192 + off)  = make_float4(a1[jj*4], a1[jj*4+1], a1[jj*4+2], a1[jj*4+3]);
            *(float4*)(rb + 16384 + off) = make_float4(a2[jj*4], a2[jj*4+1], a2[jj*4+2], a2[jj*4+3]);
            *(float4*)(rb + 24576 + off) = make_float4(a3[jj*4], a3[jj*4+1], a3[jj*4+2], a3[jj*4+3]);
        }
        __syncthreads();
    }

    // ---- layer 4: 129 -> 2, linear; waves 0..3 each take one 64-point row block
    if (wv < 4) {
        const float* hl = rb + wv * 8192;        // row of point pgB + wv*64 + lane
        const float* pb = ws + OFF4 + b * 2 * 128;
        const float* bs = ws + OFFB + 4 * 512 + b * 128;
        float q0 = bs[0], q1 = bs[1];
        #pragma unroll 2
        for (int k = 0; k < 32; ++k) {
            float4 h = *(const float4*)(hl + ((k ^ s) << 2));
            const float* w0r = pb + k * 4;          // row o=0
            const float* w1r = pb + 128 + k * 4;    // row o=1
            q0 = fmaf(h.x, w0r[0], q0); q1 = fmaf(h.x, w1r[0], q1);
            q0 = fmaf(h.y, w0r[1], q0); q1 = fmaf(h.y, w1r[1], q1);
            q0 = fmaf(h.z, w0r[2], q0); q1 = fmaf(h.z, w1r[2], q1);
            q0 = fmaf(h.w, w0r[3], q0); q1 = fmaf(h.w, w1r[3], q1);
        }
        const int pt = pgB + wv * 64 + lane;
        *(float2*)&out[((size_t)b * 65536 + pt) * 2] = make_float2(q0, q1);
    }
}

extern "C" void kernel_launch(void* const* d_in, const int* in_sizes, int n_in,
                              void* d_out, int out_size, void* d_ws, size_t ws_size,
                              hipStream_t stream)
{
    const float* coord = (const float*)d_in[0];
    const float* lat   = (const float*)d_in[1];
    float* ws = (float*)d_ws;

    // raise dynamic-LDS cap to 128 KB (module-state call, not a stream op;
    // deterministic and graph-capture-safe). Ignore result defensively.
    (void)hipFuncSetAttribute((const void*)hyponet_main,
                              hipFuncAttributeMaxDynamicSharedMemorySize, 131072);

    prep_params<<<9, 256, 0, stream>>>(
        (const float*)d_in[2], (const float*)d_in[3], (const float*)d_in[4],
        (const float*)d_in[5], (const float*)d_in[6],
        (const float*)d_in[7], (const float*)d_in[8], (const float*)d_in[9],
        (const float*)d_in[10], (const float*)d_in[11], ws);

    hyponet_main<<<1024, 512, 131072, stream>>>(coord, lat, ws, (float*)d_out);
}